// Round 12
// baseline (103.328 us; speedup 1.0000x reference)
//
#include <hip/hip_runtime.h>
#include <cstdint>

#define N_NODES 50000
#define N_EDGES 800000
#define DIM 64
#define HIDDEN 256

#define NCB 196                                  // coarse buckets (dst >> 8, 256 nodes each)
#define EPA 2048                                 // edges per partA block
#define ABLKS ((N_EDGES + EPA - 1) / EPA)        // 391
#define MAXBE 5120                               // bucket capacity (mean 4096, +16 sigma)

typedef __attribute__((ext_vector_type(8))) short bf16x8;
typedef __attribute__((ext_vector_type(4))) float f32x4;

__device__ __forceinline__ unsigned short bf16_rne(float f) {
    union { float f; uint32_t u; } cv; cv.f = f;
    uint32_t u = cv.u;
    u += 0x7FFFu + ((u >> 16) & 1u);
    return (unsigned short)(u >> 16);
}

__device__ __forceinline__ float bf2f(unsigned short us) {
    union { uint32_t u; float f; } cv; cv.u = ((uint32_t)us) << 16;
    return cv.f;
}

// tanh-form GELU via v_exp_f32; |err| vs exact erf-GELU ~1e-3 << bf16 quant.
__device__ __forceinline__ float gelu_f(float v) {
    float u = v * (0.7978845608028654f + 0.035677408136300125f * v * v);
    float e = __expf(fmaxf(fminf(2.0f * u, 80.0f), -80.0f));
    float th = (e - 1.0f) / (e + 1.0f);
    return 0.5f * v * (1.0f + th);
}

// ---------------------------------------------------------------------------
// Prep (x4 vectorized): xb = bf16(h) (h-half only, [node][64]);
// w1t[n][k] (256x128); w2t[d][j] (64x256); zero bcnt.
// ---------------------------------------------------------------------------
#define PREP_TOTAL (N_NODES * DIM + 128 * 256 + 256 * 64)   // 3,249,152 (divisible by 4)
__global__ __launch_bounds__(256)
void prep_kernel(const float* __restrict__ h, const float* __restrict__ W1,
                 const float* __restrict__ W2, unsigned short* __restrict__ xb,
                 unsigned short* __restrict__ w1t, unsigned short* __restrict__ w2t,
                 int* __restrict__ bcnt) {
    if (blockIdx.x == 0 && threadIdx.x < NCB) bcnt[threadIdx.x] = 0;
    int i4 = (blockIdx.x * 256 + threadIdx.x) * 4;
    if (i4 < N_NODES * DIM) {
        float4 v = *(const float4*)&h[i4];
        ushort4 o;
        o.x = bf16_rne(v.x); o.y = bf16_rne(v.y);
        o.z = bf16_rne(v.z); o.w = bf16_rne(v.w);
        *(ushort4*)&xb[i4] = o;                       // same layout as h
    } else if (i4 < N_NODES * DIM + 128 * 256) {
        int j = i4 - N_NODES * DIM;
        float4 v = *(const float4*)&W1[j];
        int k = j >> 8, n = j & 255;                  // 4 consecutive n, same k
        w1t[(n    ) * 128 + k] = bf16_rne(v.x);
        w1t[(n + 1) * 128 + k] = bf16_rne(v.y);
        w1t[(n + 2) * 128 + k] = bf16_rne(v.z);
        w1t[(n + 3) * 128 + k] = bf16_rne(v.w);
    } else if (i4 < PREP_TOTAL) {
        int j = i4 - N_NODES * DIM - 128 * 256;
        float4 v = *(const float4*)&W2[j];
        int jr = j >> 6, d = j & 63;                  // 4 consecutive d, same jr
        w2t[(d    ) * 256 + jr] = bf16_rne(v.x);
        w2t[(d + 1) * 256 + jr] = bf16_rne(v.y);
        w2t[(d + 2) * 256 + jr] = bf16_rne(v.z);
        w2t[(d + 3) * 256 + jr] = bf16_rne(v.w);
    }
}

// ---------------------------------------------------------------------------
// partA: bin EPA edges into NCB buckets in LDS (two global passes), reserve
// fixed-capacity bucket space via bcnt, flush coalesced runs.
// Packed edge: dst(16b) << 16 | src(16b).
// ---------------------------------------------------------------------------
__global__ __launch_bounds__(256)
void partA_kernel(const int* __restrict__ src, const int* __restrict__ dst,
                  int* __restrict__ bcnt, unsigned int* __restrict__ gbuf) {
    __shared__ unsigned int pairs[EPA];      // 8 KB
    __shared__ int cnt[NCB], offs[NCB], wc[NCB], gbase[NCB];

    const int t = threadIdx.x;
    for (int i = t; i < NCB; i += 256) cnt[i] = 0;
    __syncthreads();

    const int base = blockIdx.x * EPA;
    const int ne = (N_EDGES - base < EPA) ? (N_EDGES - base) : EPA;

    // pass 1: count
    #pragma unroll
    for (int i = 0; i < EPA / 256; ++i) {
        int e = t + i * 256;
        if (e < ne) atomicAdd(&cnt[((unsigned)dst[base + e]) >> 8], 1);
    }
    __syncthreads();

    // exclusive scan of NCB bins (wave 0, 4 bins/thread)
    if (t < 64) {
        const int b4 = t * 4;
        int c0 = (b4     < NCB) ? cnt[b4]     : 0;
        int c1 = (b4 + 1 < NCB) ? cnt[b4 + 1] : 0;
        int c2 = (b4 + 2 < NCB) ? cnt[b4 + 2] : 0;
        int c3 = (b4 + 3 < NCB) ? cnt[b4 + 3] : 0;
        const int s = c0 + c1 + c2 + c3;
        int inc = s;
        #pragma unroll
        for (int off = 1; off < 64; off <<= 1) {
            int u = __shfl_up(inc, off, 64);
            if (t >= off) inc += u;
        }
        int ex = inc - s;
        if (b4     < NCB) { offs[b4]     = ex;                wc[b4]     = ex; }
        if (b4 + 1 < NCB) { offs[b4 + 1] = ex + c0;           wc[b4 + 1] = ex + c0; }
        if (b4 + 2 < NCB) { offs[b4 + 2] = ex + c0 + c1;      wc[b4 + 2] = ex + c0 + c1; }
        if (b4 + 3 < NCB) { offs[b4 + 3] = ex + c0 + c1 + c2; wc[b4 + 3] = ex + c0 + c1 + c2; }
    }
    __syncthreads();

    // pass 2: place into LDS (re-read src/dst from L2)
    #pragma unroll
    for (int i = 0; i < EPA / 256; ++i) {
        int e = t + i * 256;
        if (e < ne) {
            unsigned int d_ = (unsigned)dst[base + e];
            unsigned int p = (d_ << 16) | (unsigned)src[base + e];
            int pos = atomicAdd(&wc[d_ >> 8], 1);
            pairs[pos] = p;
        }
    }
    __syncthreads();

    // reserve bucket space: base = b*MAXBE + cursor
    if (t < NCB) {
        int c = cnt[t];
        gbase[t] = c ? (t * MAXBE + atomicAdd(&bcnt[t], c)) : 0;
    }
    __syncthreads();

    // coalesced flush (LDS bucket-ordered -> sequential runs), overflow-guarded
    for (int p = t; p < ne; p += 256) {
        unsigned int pr = pairs[p];
        int b = (int)(pr >> 24);
        int idx = gbase[b] + (p - offs[b]);
        if (idx < (b + 1) * MAXBE) gbuf[idx] = pr;
    }
}

// ---------------------------------------------------------------------------
// partB: block (1024 thr) per bucket. LDS counting sort by dst&255; coalesced
// csr16 writes; per-node [start,end) into rng (int2).
// ---------------------------------------------------------------------------
__global__ __launch_bounds__(1024)
void partB_kernel(const unsigned int* __restrict__ gbuf, const int* __restrict__ bcnt,
                  unsigned short* __restrict__ csr16, int2* __restrict__ rng) {
    __shared__ unsigned int ep[MAXBE];   // 20 KB
    __shared__ unsigned int so[MAXBE];   // 20 KB
    __shared__ int cnt[256], offs[256], wc[256];

    const int t = threadIdx.x;
    const int b = blockIdx.x;
    if (t < 256) cnt[t] = 0;
    __syncthreads();

    const int s0 = b * MAXBE;
    int ne = bcnt[b];
    if (ne > MAXBE) ne = MAXBE;

    for (int i = t; i < ne; i += 1024) {
        unsigned int p = gbuf[s0 + i];
        ep[i] = p;
        atomicAdd(&cnt[(p >> 16) & 255], 1);
    }
    __syncthreads();

    if (t < 64) {
        const int b4 = t * 4;
        int c0 = cnt[b4], c1 = cnt[b4 + 1], c2 = cnt[b4 + 2], c3 = cnt[b4 + 3];
        const int s = c0 + c1 + c2 + c3;
        int inc = s;
        #pragma unroll
        for (int off = 1; off < 64; off <<= 1) {
            int u = __shfl_up(inc, off, 64);
            if (t >= off) inc += u;
        }
        int ex = inc - s;
        offs[b4] = ex;                    wc[b4] = ex;
        offs[b4 + 1] = ex + c0;           wc[b4 + 1] = ex + c0;
        offs[b4 + 2] = ex + c0 + c1;      wc[b4 + 2] = ex + c0 + c1;
        offs[b4 + 3] = ex + c0 + c1 + c2; wc[b4 + 3] = ex + c0 + c1 + c2;
    }
    __syncthreads();

    for (int i = t; i < ne; i += 1024) {
        unsigned int p = ep[i];
        int pos = atomicAdd(&wc[(p >> 16) & 255], 1);
        so[pos] = p;
    }
    __syncthreads();

    for (int i = t; i < ne; i += 1024)
        csr16[s0 + i] = (unsigned short)(so[i] & 0xFFFFu);

    if (t < 256) {
        int node = b * 256 + t;
        if (node < N_NODES) {
            int st = s0 + offs[t];
            rng[node] = make_int2(st, st + cnt[t]);
        }
    }
}

// ---------------------------------------------------------------------------
// Fused gather+MLP: block = 32 nodes, 4 waves.
// Phase 0: wave w gathers nodes [w*8, w*8+8): lane = dim, 8-deep unrolled
//          neighbor-row reads; mean (or own h) + h-half -> xs LDS [32][136].
// Phase 1: MFMA layer 1 (A-frags from xs), GELU -> hid LDS, layer 2, store.
// ---------------------------------------------------------------------------
__global__ __launch_bounds__(256, 4)
void gmlp_kernel(const unsigned short* __restrict__ xb,
                 const int2* __restrict__ rng,
                 const unsigned short* __restrict__ csr16,
                 const unsigned short* __restrict__ w1t,
                 const unsigned short* __restrict__ w2t,
                 const float* __restrict__ b1v,
                 const float* __restrict__ b2v,
                 float* __restrict__ out) {
    __shared__ unsigned short xs[32][136];   // 8.5 KB, row stride 272 B (16B-aligned)
    __shared__ unsigned short hid[32][264];  // 16.5 KB

    const int tid = threadIdx.x;
    const int w   = tid >> 6;
    const int l   = tid & 63;
    const int l15 = l & 15;
    const int kg  = l >> 4;                 // 0..3
    const int node0 = blockIdx.x * 32;

    // ---- phase 0: gather 8 nodes per wave ----
    for (int ni = 0; ni < 8; ++ni) {
        const int n = w * 8 + ni;
        const int node = node0 + n;
        float hv = 0.0f;
        int st = 0, en = 0;
        if (node < N_NODES) {
            hv = bf2f(xb[(size_t)node * 64 + l]);
            int2 rg = rng[node];
            st = rg.x; en = rg.y;
        }
        float acc = 0.0f;
        int i = st;
        for (; i + 7 < en; i += 8) {
            int s0 = csr16[i],     s1 = csr16[i + 1], s2 = csr16[i + 2], s3 = csr16[i + 3];
            int s4 = csr16[i + 4], s5 = csr16[i + 5], s6 = csr16[i + 6], s7 = csr16[i + 7];
            float v0 = bf2f(xb[(size_t)s0 * 64 + l]);
            float v1 = bf2f(xb[(size_t)s1 * 64 + l]);
            float v2 = bf2f(xb[(size_t)s2 * 64 + l]);
            float v3 = bf2f(xb[(size_t)s3 * 64 + l]);
            float v4 = bf2f(xb[(size_t)s4 * 64 + l]);
            float v5 = bf2f(xb[(size_t)s5 * 64 + l]);
            float v6 = bf2f(xb[(size_t)s6 * 64 + l]);
            float v7 = bf2f(xb[(size_t)s7 * 64 + l]);
            acc += ((v0 + v1) + (v2 + v3)) + ((v4 + v5) + (v6 + v7));
        }
        for (; i + 3 < en; i += 4) {
            int s0 = csr16[i], s1 = csr16[i + 1], s2 = csr16[i + 2], s3 = csr16[i + 3];
            float v0 = bf2f(xb[(size_t)s0 * 64 + l]);
            float v1 = bf2f(xb[(size_t)s1 * 64 + l]);
            float v2 = bf2f(xb[(size_t)s2 * 64 + l]);
            float v3 = bf2f(xb[(size_t)s3 * 64 + l]);
            acc += (v0 + v1) + (v2 + v3);
        }
        for (; i < en; ++i) acc += bf2f(xb[(size_t)csr16[i] * 64 + l]);
        const int degc = en - st;
        float mv = (degc > 0) ? (acc / (float)degc) : hv;
        xs[n][l]      = bf16_rne(hv);
        xs[n][64 + l] = bf16_rne(mv);
    }
    __syncthreads();

    // ---- layer 1: A-frags from xs LDS ----
    f32x4 acc[2][4];   // [node-tile][j-tile]
    #pragma unroll
    for (int a = 0; a < 2; ++a)
        #pragma unroll
        for (int b = 0; b < 4; ++b) acc[a][b] = f32x4{0.f, 0.f, 0.f, 0.f};

    #pragma unroll
    for (int s = 0; s < 4; ++s) {
        const int kofs = s * 32 + kg * 8;
        bf16x8 a[2], b[4];
        #pragma unroll
        for (int nt = 0; nt < 2; ++nt)
            a[nt] = *(const bf16x8*)&xs[nt * 16 + l15][kofs];
        #pragma unroll
        for (int jt = 0; jt < 4; ++jt)
            b[jt] = *(const bf16x8*)(w1t + ((w * 4 + jt) * 16 + l15) * 128 + kofs);
        #pragma unroll
        for (int nt = 0; nt < 2; ++nt)
            #pragma unroll
            for (int jt = 0; jt < 4; ++jt)
                acc[nt][jt] = __builtin_amdgcn_mfma_f32_16x16x32_bf16(
                    a[nt], b[jt], acc[nt][jt], 0, 0, 0);
    }

    // ---- bias + GELU -> hid LDS ----
    #pragma unroll
    for (int jt = 0; jt < 4; ++jt) {
        const int jcol = (w * 4 + jt) * 16 + l15;
        float bias = b1v[jcol];
        #pragma unroll
        for (int nt = 0; nt < 2; ++nt) {
            #pragma unroll
            for (int r = 0; r < 4; ++r) {
                float v = acc[nt][jt][r] + bias;
                hid[nt * 16 + kg * 4 + r][jcol] = bf16_rne(gelu_f(v));
            }
        }
    }
    __syncthreads();

    // ---- layer 2: wave w -> d-tile w ----
    f32x4 acc2[2];
    #pragma unroll
    for (int a = 0; a < 2; ++a) acc2[a] = f32x4{0.f, 0.f, 0.f, 0.f};

    #pragma unroll
    for (int s = 0; s < 8; ++s) {
        const int kofs = s * 32 + kg * 8;
        bf16x8 bb = *(const bf16x8*)(w2t + (w * 16 + l15) * 256 + kofs);
        #pragma unroll
        for (int nt = 0; nt < 2; ++nt) {
            bf16x8 aa = *(const bf16x8*)&hid[nt * 16 + l15][kofs];
            acc2[nt] = __builtin_amdgcn_mfma_f32_16x16x32_bf16(aa, bb, acc2[nt], 0, 0, 0);
        }
    }

    float bias2 = b2v[w * 16 + l15];
    #pragma unroll
    for (int nt = 0; nt < 2; ++nt) {
        #pragma unroll
        for (int r = 0; r < 4; ++r) {
            int node = node0 + nt * 16 + kg * 4 + r;
            if (node < N_NODES)
                out[(size_t)node * DIM + w * 16 + l15] = acc2[nt][r] + bias2;
        }
    }
}

// ---------------------------------------------------------------------------
extern "C" void kernel_launch(void* const* d_in, const int* in_sizes, int n_in,
                              void* d_out, int out_size, void* d_ws, size_t ws_size,
                              hipStream_t stream) {
    const float* h  = (const float*)d_in[0];
    const int* eidx = (const int*)d_in[1];   // [2, N_EDGES]: src row then dst row
    const float* W1 = (const float*)d_in[2];
    const float* b1 = (const float*)d_in[3];
    const float* W2 = (const float*)d_in[4];
    const float* b2 = (const float*)d_in[5];
    float* out = (float*)d_out;

    const int* src = eidx;
    const int* dst = eidx + N_EDGES;

    // workspace layout
    unsigned short* xb    = (unsigned short*)d_ws;                 // N_NODES*64 ushort (h-half only)
    unsigned short* w1t   = xb + (size_t)N_NODES * 64;             // 32,768
    unsigned short* w2t   = w1t + 128 * 256;                       // 16,384
    unsigned int*   gbuf  = (unsigned int*)(w2t + 256 * 64);       // NCB*MAXBE uint
    unsigned short* csr16 = (unsigned short*)(gbuf + NCB * MAXBE); // NCB*MAXBE ushort
    int*  bcnt = (int*)(csr16 + NCB * MAXBE);                      // NCB
    int2* rng  = (int2*)(bcnt + NCB);                              // N_NODES (8B-aligned)

    prep_kernel<<<(PREP_TOTAL / 4 + 255) / 256, 256, 0, stream>>>(h, W1, W2, xb, w1t, w2t, bcnt);
    partA_kernel<<<ABLKS, 256, 0, stream>>>(src, dst, bcnt, gbuf);
    partB_kernel<<<NCB, 1024, 0, stream>>>(gbuf, bcnt, csr16, rng);
    {
        int grid = (N_NODES + 31) / 32;
        gmlp_kernel<<<grid, 256, 0, stream>>>(xb, rng, csr16, w1t, w2t, b1, b2, out);
    }
}

// Round 13
// 89.365 us; speedup vs baseline: 1.1562x; 1.1562x over previous
//
#include <hip/hip_runtime.h>
#include <cstdint>

#define N_NODES 50000
#define N_EDGES 800000
#define DIM 64
#define HIDDEN 256

#define NCB 196                                  // coarse buckets (dst >> 8, 256 nodes each)
#define EPA 2048                                 // edges per partA block
#define ABLKS ((N_EDGES + EPA - 1) / EPA)        // 391
#define MAXBE 5120                               // bucket capacity (mean 4096, +16 sigma)

typedef __attribute__((ext_vector_type(8))) short bf16x8;
typedef __attribute__((ext_vector_type(4))) float f32x4;

__device__ __forceinline__ unsigned short bf16_rne(float f) {
    union { float f; uint32_t u; } cv; cv.f = f;
    uint32_t u = cv.u;
    u += 0x7FFFu + ((u >> 16) & 1u);
    return (unsigned short)(u >> 16);
}

__device__ __forceinline__ float bf2f(unsigned short us) {
    union { uint32_t u; float f; } cv; cv.u = ((uint32_t)us) << 16;
    return cv.f;
}

// tanh-form GELU via v_exp_f32; |err| vs exact erf-GELU ~1e-3 << bf16 quant.
__device__ __forceinline__ float gelu_f(float v) {
    float u = v * (0.7978845608028654f + 0.035677408136300125f * v * v);
    float e = __expf(fmaxf(fminf(2.0f * u, 80.0f), -80.0f));
    float th = (e - 1.0f) / (e + 1.0f);
    return 0.5f * v * (1.0f + th);
}

// ---------------------------------------------------------------------------
// Prep (x4 vectorized): xb h-half (rows of 128 ushorts: [h(64) | mean(64)]);
// w1t[n][k] (256x128); w2t[d][j] (64x256); zero bcnt.
// ---------------------------------------------------------------------------
#define PREP_TOTAL (N_NODES * DIM + 128 * 256 + 256 * 64)   // divisible by 4
__global__ __launch_bounds__(256)
void prep_kernel(const float* __restrict__ h, const float* __restrict__ W1,
                 const float* __restrict__ W2, unsigned short* __restrict__ xb,
                 unsigned short* __restrict__ w1t, unsigned short* __restrict__ w2t,
                 int* __restrict__ bcnt) {
    if (blockIdx.x == 0 && threadIdx.x < NCB) bcnt[threadIdx.x] = 0;
    int i4 = (blockIdx.x * 256 + threadIdx.x) * 4;
    if (i4 < N_NODES * DIM) {
        float4 v = *(const float4*)&h[i4];
        ushort4 o;
        o.x = bf16_rne(v.x); o.y = bf16_rne(v.y);
        o.z = bf16_rne(v.z); o.w = bf16_rne(v.w);
        int node = i4 >> 6, d = i4 & 63;
        *(ushort4*)&xb[(size_t)node * 128 + d] = o;
    } else if (i4 < N_NODES * DIM + 128 * 256) {
        int j = i4 - N_NODES * DIM;
        float4 v = *(const float4*)&W1[j];
        int k = j >> 8, n = j & 255;                  // 4 consecutive n, same k
        w1t[(n    ) * 128 + k] = bf16_rne(v.x);
        w1t[(n + 1) * 128 + k] = bf16_rne(v.y);
        w1t[(n + 2) * 128 + k] = bf16_rne(v.z);
        w1t[(n + 3) * 128 + k] = bf16_rne(v.w);
    } else if (i4 < PREP_TOTAL) {
        int j = i4 - N_NODES * DIM - 128 * 256;
        float4 v = *(const float4*)&W2[j];
        int jr = j >> 6, d = j & 63;                  // 4 consecutive d, same jr
        w2t[(d    ) * 256 + jr] = bf16_rne(v.x);
        w2t[(d + 1) * 256 + jr] = bf16_rne(v.y);
        w2t[(d + 2) * 256 + jr] = bf16_rne(v.z);
        w2t[(d + 3) * 256 + jr] = bf16_rne(v.w);
    }
}

// ---------------------------------------------------------------------------
// partA: bin EPA edges into NCB buckets in LDS (two global passes), reserve
// fixed-capacity bucket space via bcnt, flush coalesced runs.
// Packed edge: dst(16b) << 16 | src(16b).
// ---------------------------------------------------------------------------
__global__ __launch_bounds__(256)
void partA_kernel(const int* __restrict__ src, const int* __restrict__ dst,
                  int* __restrict__ bcnt, unsigned int* __restrict__ gbuf) {
    __shared__ unsigned int pairs[EPA];      // 8 KB
    __shared__ int cnt[NCB], offs[NCB], wc[NCB], gbase[NCB];

    const int t = threadIdx.x;
    for (int i = t; i < NCB; i += 256) cnt[i] = 0;
    __syncthreads();

    const int base = blockIdx.x * EPA;
    const int ne = (N_EDGES - base < EPA) ? (N_EDGES - base) : EPA;

    // pass 1: count
    #pragma unroll
    for (int i = 0; i < EPA / 256; ++i) {
        int e = t + i * 256;
        if (e < ne) atomicAdd(&cnt[((unsigned)dst[base + e]) >> 8], 1);
    }
    __syncthreads();

    // exclusive scan of NCB bins (wave 0, 4 bins/thread)
    if (t < 64) {
        const int b4 = t * 4;
        int c0 = (b4     < NCB) ? cnt[b4]     : 0;
        int c1 = (b4 + 1 < NCB) ? cnt[b4 + 1] : 0;
        int c2 = (b4 + 2 < NCB) ? cnt[b4 + 2] : 0;
        int c3 = (b4 + 3 < NCB) ? cnt[b4 + 3] : 0;
        const int s = c0 + c1 + c2 + c3;
        int inc = s;
        #pragma unroll
        for (int off = 1; off < 64; off <<= 1) {
            int u = __shfl_up(inc, off, 64);
            if (t >= off) inc += u;
        }
        int ex = inc - s;
        if (b4     < NCB) { offs[b4]     = ex;                wc[b4]     = ex; }
        if (b4 + 1 < NCB) { offs[b4 + 1] = ex + c0;           wc[b4 + 1] = ex + c0; }
        if (b4 + 2 < NCB) { offs[b4 + 2] = ex + c0 + c1;      wc[b4 + 2] = ex + c0 + c1; }
        if (b4 + 3 < NCB) { offs[b4 + 3] = ex + c0 + c1 + c2; wc[b4 + 3] = ex + c0 + c1 + c2; }
    }
    __syncthreads();

    // pass 2: place into LDS (re-read src/dst from L2)
    #pragma unroll
    for (int i = 0; i < EPA / 256; ++i) {
        int e = t + i * 256;
        if (e < ne) {
            unsigned int d_ = (unsigned)dst[base + e];
            unsigned int p = (d_ << 16) | (unsigned)src[base + e];
            int pos = atomicAdd(&wc[d_ >> 8], 1);
            pairs[pos] = p;
        }
    }
    __syncthreads();

    // reserve bucket space: base = b*MAXBE + cursor
    if (t < NCB) {
        int c = cnt[t];
        gbase[t] = c ? (t * MAXBE + atomicAdd(&bcnt[t], c)) : 0;
    }
    __syncthreads();

    // coalesced flush (LDS bucket-ordered -> sequential runs), overflow-guarded
    for (int p = t; p < ne; p += 256) {
        unsigned int pr = pairs[p];
        int b = (int)(pr >> 24);
        int idx = gbase[b] + (p - offs[b]);
        if (idx < (b + 1) * MAXBE) gbuf[idx] = pr;
    }
}

// ---------------------------------------------------------------------------
// partB: block (1024 thr) per bucket. LDS counting sort by dst&255; coalesced
// csr16 writes; per-node [start,end) into rng (int2).
// ---------------------------------------------------------------------------
__global__ __launch_bounds__(1024)
void partB_kernel(const unsigned int* __restrict__ gbuf, const int* __restrict__ bcnt,
                  unsigned short* __restrict__ csr16, int2* __restrict__ rng) {
    __shared__ unsigned int ep[MAXBE];   // 20 KB
    __shared__ unsigned int so[MAXBE];   // 20 KB
    __shared__ int cnt[256], offs[256], wc[256];

    const int t = threadIdx.x;
    const int b = blockIdx.x;
    if (t < 256) cnt[t] = 0;
    __syncthreads();

    const int s0 = b * MAXBE;
    int ne = bcnt[b];
    if (ne > MAXBE) ne = MAXBE;

    for (int i = t; i < ne; i += 1024) {
        unsigned int p = gbuf[s0 + i];
        ep[i] = p;
        atomicAdd(&cnt[(p >> 16) & 255], 1);
    }
    __syncthreads();

    if (t < 64) {
        const int b4 = t * 4;
        int c0 = cnt[b4], c1 = cnt[b4 + 1], c2 = cnt[b4 + 2], c3 = cnt[b4 + 3];
        const int s = c0 + c1 + c2 + c3;
        int inc = s;
        #pragma unroll
        for (int off = 1; off < 64; off <<= 1) {
            int u = __shfl_up(inc, off, 64);
            if (t >= off) inc += u;
        }
        int ex = inc - s;
        offs[b4] = ex;                    wc[b4] = ex;
        offs[b4 + 1] = ex + c0;           wc[b4 + 1] = ex + c0;
        offs[b4 + 2] = ex + c0 + c1;      wc[b4 + 2] = ex + c0 + c1;
        offs[b4 + 3] = ex + c0 + c1 + c2; wc[b4 + 3] = ex + c0 + c1 + c2;
    }
    __syncthreads();

    for (int i = t; i < ne; i += 1024) {
        unsigned int p = ep[i];
        int pos = atomicAdd(&wc[(p >> 16) & 255], 1);
        so[pos] = p;
    }
    __syncthreads();

    for (int i = t; i < ne; i += 1024)
        csr16[s0 + i] = (unsigned short)(so[i] & 0xFFFFu);

    if (t < 256) {
        int node = b * 256 + t;
        if (node < N_NODES) {
            int st = s0 + offs[t];
            rng[node] = make_int2(st, st + cnt[t]);
        }
    }
}

// ---------------------------------------------------------------------------
// Gather: one wave per node. Lane l = dim-pair (l&31) of edge-stream (l>>5):
// each uint load covers 2 dims, the two half-waves cover 2 edges/instruction.
// Cross-half shfl_xor reduce; packed-uint write of mean (or own h).
// ---------------------------------------------------------------------------
__global__ __launch_bounds__(256)
void gather_kernel(const int2* __restrict__ rng,
                   const unsigned short* __restrict__ csr16,
                   unsigned short* __restrict__ xb) {
    const unsigned int* xbu = (const unsigned int*)xb;   // rows of 64 uints
    int node = blockIdx.x * 4 + (threadIdx.x >> 6);
    if (node >= N_NODES) return;
    const int l = threadIdx.x & 63;
    const int p = l & 31;
    const int half = l >> 5;
    int2 rg = rng[node];
    const int st = rg.x, en = rg.y;
    const int degc = en - st;
    float a0 = 0.0f, a1 = 0.0f;
    int i = st + half;
    for (; i + 6 < en; i += 8) {
        int s0 = csr16[i];
        int s1 = csr16[i + 2];
        int s2 = csr16[i + 4];
        int s3 = csr16[i + 6];
        unsigned int u0 = xbu[(size_t)s0 * 64 + p];
        unsigned int u1 = xbu[(size_t)s1 * 64 + p];
        unsigned int u2 = xbu[(size_t)s2 * 64 + p];
        unsigned int u3 = xbu[(size_t)s3 * 64 + p];
        a0 += (bf2f((unsigned short)u0) + bf2f((unsigned short)u1))
            + (bf2f((unsigned short)u2) + bf2f((unsigned short)u3));
        a1 += (bf2f((unsigned short)(u0 >> 16)) + bf2f((unsigned short)(u1 >> 16)))
            + (bf2f((unsigned short)(u2 >> 16)) + bf2f((unsigned short)(u3 >> 16)));
    }
    for (; i < en; i += 2) {
        int s = csr16[i];
        unsigned int u = xbu[(size_t)s * 64 + p];
        a0 += bf2f((unsigned short)u);
        a1 += bf2f((unsigned short)(u >> 16));
    }
    a0 += __shfl_xor(a0, 32, 64);
    a1 += __shfl_xor(a1, 32, 64);
    if (half == 0) {
        unsigned int res;
        if (degc > 0) {
            float inv = 1.0f / (float)degc;
            res = ((unsigned int)bf16_rne(a1 * inv) << 16) | bf16_rne(a0 * inv);
        } else {
            res = xbu[(size_t)node * 64 + p];
        }
        ((unsigned int*)xb)[(size_t)node * 64 + 32 + p] = res;
    }
}

// ---------------------------------------------------------------------------
// MFMA MLP: block = 32 nodes, 4 waves (1563 blocks, 6 blocks/CU target).
// ---------------------------------------------------------------------------
__global__ __launch_bounds__(256, 6)
void mlp_mfma_kernel(const unsigned short* __restrict__ xb,
                     const unsigned short* __restrict__ w1t,
                     const unsigned short* __restrict__ w2t,
                     const float* __restrict__ b1v,
                     const float* __restrict__ b2v,
                     float* __restrict__ out) {
    __shared__ unsigned short hid[32][264];

    const int tid = threadIdx.x;
    const int w   = tid >> 6;
    const int l   = tid & 63;
    const int l15 = l & 15;
    const int kg  = l >> 4;                 // 0..3
    const int node0 = blockIdx.x * 32;

    int arow[2];
    #pragma unroll
    for (int nt = 0; nt < 2; ++nt) {
        int r = node0 + nt * 16 + l15;
        arow[nt] = (r < N_NODES) ? r : (N_NODES - 1);
    }

    // ---- layer 1 ----
    f32x4 acc[2][4];   // [node-tile][j-tile]
    #pragma unroll
    for (int a = 0; a < 2; ++a)
        #pragma unroll
        for (int b = 0; b < 4; ++b) acc[a][b] = f32x4{0.f, 0.f, 0.f, 0.f};

    #pragma unroll
    for (int s = 0; s < 4; ++s) {
        const int kofs = s * 32 + kg * 8;
        bf16x8 a[2], b[4];
        #pragma unroll
        for (int nt = 0; nt < 2; ++nt)
            a[nt] = *(const bf16x8*)(xb + (size_t)arow[nt] * 128 + kofs);
        #pragma unroll
        for (int jt = 0; jt < 4; ++jt)
            b[jt] = *(const bf16x8*)(w1t + ((w * 4 + jt) * 16 + l15) * 128 + kofs);
        #pragma unroll
        for (int nt = 0; nt < 2; ++nt)
            #pragma unroll
            for (int jt = 0; jt < 4; ++jt)
                acc[nt][jt] = __builtin_amdgcn_mfma_f32_16x16x32_bf16(
                    a[nt], b[jt], acc[nt][jt], 0, 0, 0);
    }

    // ---- bias + GELU -> hid LDS ----
    #pragma unroll
    for (int jt = 0; jt < 4; ++jt) {
        const int jcol = (w * 4 + jt) * 16 + l15;
        float bias = b1v[jcol];
        #pragma unroll
        for (int nt = 0; nt < 2; ++nt) {
            #pragma unroll
            for (int r = 0; r < 4; ++r) {
                float v = acc[nt][jt][r] + bias;
                hid[nt * 16 + kg * 4 + r][jcol] = bf16_rne(gelu_f(v));
            }
        }
    }
    __syncthreads();

    // ---- layer 2: wave w -> d-tile w ----
    f32x4 acc2[2];
    #pragma unroll
    for (int a = 0; a < 2; ++a) acc2[a] = f32x4{0.f, 0.f, 0.f, 0.f};

    #pragma unroll
    for (int s = 0; s < 8; ++s) {
        const int kofs = s * 32 + kg * 8;
        bf16x8 bb = *(const bf16x8*)(w2t + (w * 16 + l15) * 256 + kofs);
        #pragma unroll
        for (int nt = 0; nt < 2; ++nt) {
            bf16x8 aa = *(const bf16x8*)&hid[nt * 16 + l15][kofs];
            acc2[nt] = __builtin_amdgcn_mfma_f32_16x16x32_bf16(aa, bb, acc2[nt], 0, 0, 0);
        }
    }

    float bias2 = b2v[w * 16 + l15];
    #pragma unroll
    for (int nt = 0; nt < 2; ++nt) {
        #pragma unroll
        for (int r = 0; r < 4; ++r) {
            int node = node0 + nt * 16 + kg * 4 + r;
            if (node < N_NODES)
                out[(size_t)node * DIM + w * 16 + l15] = acc2[nt][r] + bias2;
        }
    }
}

// ---------------------------------------------------------------------------
extern "C" void kernel_launch(void* const* d_in, const int* in_sizes, int n_in,
                              void* d_out, int out_size, void* d_ws, size_t ws_size,
                              hipStream_t stream) {
    const float* h  = (const float*)d_in[0];
    const int* eidx = (const int*)d_in[1];   // [2, N_EDGES]: src row then dst row
    const float* W1 = (const float*)d_in[2];
    const float* b1 = (const float*)d_in[3];
    const float* W2 = (const float*)d_in[4];
    const float* b2 = (const float*)d_in[5];
    float* out = (float*)d_out;

    const int* src = eidx;
    const int* dst = eidx + N_EDGES;

    // workspace layout
    unsigned short* xb    = (unsigned short*)d_ws;                 // N_NODES*128 ushort
    unsigned short* w1t   = xb + (size_t)N_NODES * 128;            // 32,768
    unsigned short* w2t   = w1t + 128 * 256;                       // 16,384
    unsigned int*   gbuf  = (unsigned int*)(w2t + 256 * 64);       // NCB*MAXBE uint
    unsigned short* csr16 = (unsigned short*)(gbuf + NCB * MAXBE); // NCB*MAXBE ushort
    int*  bcnt = (int*)(csr16 + NCB * MAXBE);                      // NCB
    int2* rng  = (int2*)(bcnt + NCB);                              // N_NODES (8B-aligned)

    prep_kernel<<<(PREP_TOTAL / 4 + 255) / 256, 256, 0, stream>>>(h, W1, W2, xb, w1t, w2t, bcnt);
    partA_kernel<<<ABLKS, 256, 0, stream>>>(src, dst, bcnt, gbuf);
    partB_kernel<<<NCB, 1024, 0, stream>>>(gbuf, bcnt, csr16, rng);
    {
        int grid = (N_NODES + 3) / 4;
        gather_kernel<<<grid, 256, 0, stream>>>(rng, csr16, xb);
    }
    {
        int grid = (N_NODES + 31) / 32;
        mlp_mfma_kernel<<<grid, 256, 0, stream>>>(xb, w1t, w2t, b1, b2, out);
    }
}

// Round 14
// 87.579 us; speedup vs baseline: 1.1798x; 1.0204x over previous
//
#include <hip/hip_runtime.h>
#include <cstdint>

#define N_NODES 50000
#define N_EDGES 800000
#define DIM 64
#define HIDDEN 256

#define NCB 196                                  // coarse buckets (dst >> 8, 256 nodes each)
#define EPA 2048                                 // edges per partA block
#define ABLKS ((N_EDGES + EPA - 1) / EPA)        // 391
#define MAXBE 5120                               // bucket capacity (mean 4096, +16 sigma)

typedef __attribute__((ext_vector_type(8))) short bf16x8;
typedef __attribute__((ext_vector_type(4))) float f32x4;

__device__ __forceinline__ unsigned short bf16_rne(float f) {
    union { float f; uint32_t u; } cv; cv.f = f;
    uint32_t u = cv.u;
    u += 0x7FFFu + ((u >> 16) & 1u);
    return (unsigned short)(u >> 16);
}

__device__ __forceinline__ float bf2f(unsigned short us) {
    union { uint32_t u; float f; } cv; cv.u = ((uint32_t)us) << 16;
    return cv.f;
}

// tanh-form GELU via v_exp_f32; |err| vs exact erf-GELU ~1e-3 << bf16 quant.
__device__ __forceinline__ float gelu_f(float v) {
    float u = v * (0.7978845608028654f + 0.035677408136300125f * v * v);
    float e = __expf(fmaxf(fminf(2.0f * u, 80.0f), -80.0f));
    float th = (e - 1.0f) / (e + 1.0f);
    return 0.5f * v * (1.0f + th);
}

// ---------------------------------------------------------------------------
// Prep (x4 vectorized): xb rows of 128 ushorts [h(64) | mean(64)];
// w1t[n][k] (256x128); w2t[d][j] (64x256); zero bcnt.
// ---------------------------------------------------------------------------
#define PREP_TOTAL (N_NODES * DIM + 128 * 256 + 256 * 64)   // divisible by 4
__global__ __launch_bounds__(256)
void prep_kernel(const float* __restrict__ h, const float* __restrict__ W1,
                 const float* __restrict__ W2, unsigned short* __restrict__ xb,
                 unsigned short* __restrict__ w1t, unsigned short* __restrict__ w2t,
                 int* __restrict__ bcnt) {
    if (blockIdx.x == 0 && threadIdx.x < NCB) bcnt[threadIdx.x] = 0;
    int i4 = (blockIdx.x * 256 + threadIdx.x) * 4;
    if (i4 < N_NODES * DIM) {
        float4 v = *(const float4*)&h[i4];
        ushort4 o;
        o.x = bf16_rne(v.x); o.y = bf16_rne(v.y);
        o.z = bf16_rne(v.z); o.w = bf16_rne(v.w);
        int node = i4 >> 6, d = i4 & 63;
        *(ushort4*)&xb[(size_t)node * 128 + d] = o;
    } else if (i4 < N_NODES * DIM + 128 * 256) {
        int j = i4 - N_NODES * DIM;
        float4 v = *(const float4*)&W1[j];
        int k = j >> 8, n = j & 255;                  // 4 consecutive n, same k
        w1t[(n    ) * 128 + k] = bf16_rne(v.x);
        w1t[(n + 1) * 128 + k] = bf16_rne(v.y);
        w1t[(n + 2) * 128 + k] = bf16_rne(v.z);
        w1t[(n + 3) * 128 + k] = bf16_rne(v.w);
    } else if (i4 < PREP_TOTAL) {
        int j = i4 - N_NODES * DIM - 128 * 256;
        float4 v = *(const float4*)&W2[j];
        int jr = j >> 6, d = j & 63;                  // 4 consecutive d, same jr
        w2t[(d    ) * 256 + jr] = bf16_rne(v.x);
        w2t[(d + 1) * 256 + jr] = bf16_rne(v.y);
        w2t[(d + 2) * 256 + jr] = bf16_rne(v.z);
        w2t[(d + 3) * 256 + jr] = bf16_rne(v.w);
    }
}

// ---------------------------------------------------------------------------
// partA: bin EPA edges into NCB buckets in LDS (two global passes), reserve
// fixed-capacity bucket space via bcnt, flush coalesced runs.
// Packed edge: dst(16b) << 16 | src(16b).
// ---------------------------------------------------------------------------
__global__ __launch_bounds__(256)
void partA_kernel(const int* __restrict__ src, const int* __restrict__ dst,
                  int* __restrict__ bcnt, unsigned int* __restrict__ gbuf) {
    __shared__ unsigned int pairs[EPA];      // 8 KB
    __shared__ int cnt[NCB], offs[NCB], wc[NCB], gbase[NCB];

    const int t = threadIdx.x;
    for (int i = t; i < NCB; i += 256) cnt[i] = 0;
    __syncthreads();

    const int base = blockIdx.x * EPA;
    const int ne = (N_EDGES - base < EPA) ? (N_EDGES - base) : EPA;

    // pass 1: count
    #pragma unroll
    for (int i = 0; i < EPA / 256; ++i) {
        int e = t + i * 256;
        if (e < ne) atomicAdd(&cnt[((unsigned)dst[base + e]) >> 8], 1);
    }
    __syncthreads();

    // exclusive scan of NCB bins (wave 0, 4 bins/thread)
    if (t < 64) {
        const int b4 = t * 4;
        int c0 = (b4     < NCB) ? cnt[b4]     : 0;
        int c1 = (b4 + 1 < NCB) ? cnt[b4 + 1] : 0;
        int c2 = (b4 + 2 < NCB) ? cnt[b4 + 2] : 0;
        int c3 = (b4 + 3 < NCB) ? cnt[b4 + 3] : 0;
        const int s = c0 + c1 + c2 + c3;
        int inc = s;
        #pragma unroll
        for (int off = 1; off < 64; off <<= 1) {
            int u = __shfl_up(inc, off, 64);
            if (t >= off) inc += u;
        }
        int ex = inc - s;
        if (b4     < NCB) { offs[b4]     = ex;                wc[b4]     = ex; }
        if (b4 + 1 < NCB) { offs[b4 + 1] = ex + c0;           wc[b4 + 1] = ex + c0; }
        if (b4 + 2 < NCB) { offs[b4 + 2] = ex + c0 + c1;      wc[b4 + 2] = ex + c0 + c1; }
        if (b4 + 3 < NCB) { offs[b4 + 3] = ex + c0 + c1 + c2; wc[b4 + 3] = ex + c0 + c1 + c2; }
    }
    __syncthreads();

    // pass 2: place into LDS (re-read src/dst from L2)
    #pragma unroll
    for (int i = 0; i < EPA / 256; ++i) {
        int e = t + i * 256;
        if (e < ne) {
            unsigned int d_ = (unsigned)dst[base + e];
            unsigned int p = (d_ << 16) | (unsigned)src[base + e];
            int pos = atomicAdd(&wc[d_ >> 8], 1);
            pairs[pos] = p;
        }
    }
    __syncthreads();

    // reserve bucket space: base = b*MAXBE + cursor
    if (t < NCB) {
        int c = cnt[t];
        gbase[t] = c ? (t * MAXBE + atomicAdd(&bcnt[t], c)) : 0;
    }
    __syncthreads();

    // coalesced flush (LDS bucket-ordered -> sequential runs), overflow-guarded
    for (int p = t; p < ne; p += 256) {
        unsigned int pr = pairs[p];
        int b = (int)(pr >> 24);
        int idx = gbase[b] + (p - offs[b]);
        if (idx < (b + 1) * MAXBE) gbuf[idx] = pr;
    }
}

// ---------------------------------------------------------------------------
// partB: block (1024 thr) per bucket. LDS counting sort by dst&255; coalesced
// csr16 writes; per-node [start,end) into rng (int2).
// ---------------------------------------------------------------------------
__global__ __launch_bounds__(1024)
void partB_kernel(const unsigned int* __restrict__ gbuf, const int* __restrict__ bcnt,
                  unsigned short* __restrict__ csr16, int2* __restrict__ rng) {
    __shared__ unsigned int ep[MAXBE];   // 20 KB
    __shared__ unsigned int so[MAXBE];   // 20 KB
    __shared__ int cnt[256], offs[256], wc[256];

    const int t = threadIdx.x;
    const int b = blockIdx.x;
    if (t < 256) cnt[t] = 0;
    __syncthreads();

    const int s0 = b * MAXBE;
    int ne = bcnt[b];
    if (ne > MAXBE) ne = MAXBE;

    for (int i = t; i < ne; i += 1024) {
        unsigned int p = gbuf[s0 + i];
        ep[i] = p;
        atomicAdd(&cnt[(p >> 16) & 255], 1);
    }
    __syncthreads();

    if (t < 64) {
        const int b4 = t * 4;
        int c0 = cnt[b4], c1 = cnt[b4 + 1], c2 = cnt[b4 + 2], c3 = cnt[b4 + 3];
        const int s = c0 + c1 + c2 + c3;
        int inc = s;
        #pragma unroll
        for (int off = 1; off < 64; off <<= 1) {
            int u = __shfl_up(inc, off, 64);
            if (t >= off) inc += u;
        }
        int ex = inc - s;
        offs[b4] = ex;                    wc[b4] = ex;
        offs[b4 + 1] = ex + c0;           wc[b4 + 1] = ex + c0;
        offs[b4 + 2] = ex + c0 + c1;      wc[b4 + 2] = ex + c0 + c1;
        offs[b4 + 3] = ex + c0 + c1 + c2; wc[b4 + 3] = ex + c0 + c1 + c2;
    }
    __syncthreads();

    for (int i = t; i < ne; i += 1024) {
        unsigned int p = ep[i];
        int pos = atomicAdd(&wc[(p >> 16) & 255], 1);
        so[pos] = p;
    }
    __syncthreads();

    for (int i = t; i < ne; i += 1024)
        csr16[s0 + i] = (unsigned short)(so[i] & 0xFFFFu);

    if (t < 256) {
        int node = b * 256 + t;
        if (node < N_NODES) {
            int st = s0 + offs[t];
            rng[node] = make_int2(st, st + cnt[t]);
        }
    }
}

// ---------------------------------------------------------------------------
// Gather: one wave per node. Lane l = dim-quad (l&15) of edge-stream (l>>4):
// each uint2 load covers 4 dims; 4 quarter-wave streams cover 4 edges per
// wave-issue. Cross-stream shfl_xor(16,32) reduce; uint2 write of the mean.
// ---------------------------------------------------------------------------
__global__ __launch_bounds__(256)
void gather_kernel(const int2* __restrict__ rng,
                   const unsigned short* __restrict__ csr16,
                   unsigned short* __restrict__ xb) {
    const uint2* xbu = (const uint2*)xb;   // rows of 32 uint2; h-half = [0,16)
    int node = blockIdx.x * 4 + (threadIdx.x >> 6);
    if (node >= N_NODES) return;
    const int l = threadIdx.x & 63;
    const int q = l & 15;
    const int sdx = l >> 4;                // stream 0..3
    int2 rg = rng[node];
    const int st = rg.x, en = rg.y;
    const int degc = en - st;
    float a0 = 0.0f, a1 = 0.0f, a2 = 0.0f, a3 = 0.0f;
    int i = st + sdx;
    for (; i + 4 < en; i += 8) {
        int s0 = csr16[i];
        int s1 = csr16[i + 4];
        uint2 u0 = xbu[(size_t)s0 * 32 + q];
        uint2 u1 = xbu[(size_t)s1 * 32 + q];
        a0 += bf2f((unsigned short)u0.x) + bf2f((unsigned short)u1.x);
        a1 += bf2f((unsigned short)(u0.x >> 16)) + bf2f((unsigned short)(u1.x >> 16));
        a2 += bf2f((unsigned short)u0.y) + bf2f((unsigned short)u1.y);
        a3 += bf2f((unsigned short)(u0.y >> 16)) + bf2f((unsigned short)(u1.y >> 16));
    }
    for (; i < en; i += 4) {
        int s = csr16[i];
        uint2 u = xbu[(size_t)s * 32 + q];
        a0 += bf2f((unsigned short)u.x);
        a1 += bf2f((unsigned short)(u.x >> 16));
        a2 += bf2f((unsigned short)u.y);
        a3 += bf2f((unsigned short)(u.y >> 16));
    }
    a0 += __shfl_xor(a0, 16, 64); a0 += __shfl_xor(a0, 32, 64);
    a1 += __shfl_xor(a1, 16, 64); a1 += __shfl_xor(a1, 32, 64);
    a2 += __shfl_xor(a2, 16, 64); a2 += __shfl_xor(a2, 32, 64);
    a3 += __shfl_xor(a3, 16, 64); a3 += __shfl_xor(a3, 32, 64);
    if (sdx == 0) {
        uint2 res;
        if (degc > 0) {
            float inv = 1.0f / (float)degc;
            res.x = ((unsigned int)bf16_rne(a1 * inv) << 16) | bf16_rne(a0 * inv);
            res.y = ((unsigned int)bf16_rne(a3 * inv) << 16) | bf16_rne(a2 * inv);
        } else {
            res = xbu[(size_t)node * 32 + q];
        }
        ((uint2*)xb)[(size_t)node * 32 + 16 + q] = res;
    }
}

// ---------------------------------------------------------------------------
// MFMA MLP: block = 32 nodes, 4 waves (1563 blocks, 6 blocks/CU target).
// ---------------------------------------------------------------------------
__global__ __launch_bounds__(256, 6)
void mlp_mfma_kernel(const unsigned short* __restrict__ xb,
                     const unsigned short* __restrict__ w1t,
                     const unsigned short* __restrict__ w2t,
                     const float* __restrict__ b1v,
                     const float* __restrict__ b2v,
                     float* __restrict__ out) {
    __shared__ unsigned short hid[32][264];

    const int tid = threadIdx.x;
    const int w   = tid >> 6;
    const int l   = tid & 63;
    const int l15 = l & 15;
    const int kg  = l >> 4;                 // 0..3
    const int node0 = blockIdx.x * 32;

    int arow[2];
    #pragma unroll
    for (int nt = 0; nt < 2; ++nt) {
        int r = node0 + nt * 16 + l15;
        arow[nt] = (r < N_NODES) ? r : (N_NODES - 1);
    }

    // ---- layer 1 ----
    f32x4 acc[2][4];   // [node-tile][j-tile]
    #pragma unroll
    for (int a = 0; a < 2; ++a)
        #pragma unroll
        for (int b = 0; b < 4; ++b) acc[a][b] = f32x4{0.f, 0.f, 0.f, 0.f};

    #pragma unroll
    for (int s = 0; s < 4; ++s) {
        const int kofs = s * 32 + kg * 8;
        bf16x8 a[2], b[4];
        #pragma unroll
        for (int nt = 0; nt < 2; ++nt)
            a[nt] = *(const bf16x8*)(xb + (size_t)arow[nt] * 128 + kofs);
        #pragma unroll
        for (int jt = 0; jt < 4; ++jt)
            b[jt] = *(const bf16x8*)(w1t + ((w * 4 + jt) * 16 + l15) * 128 + kofs);
        #pragma unroll
        for (int nt = 0; nt < 2; ++nt)
            #pragma unroll
            for (int jt = 0; jt < 4; ++jt)
                acc[nt][jt] = __builtin_amdgcn_mfma_f32_16x16x32_bf16(
                    a[nt], b[jt], acc[nt][jt], 0, 0, 0);
    }

    // ---- bias + GELU -> hid LDS ----
    #pragma unroll
    for (int jt = 0; jt < 4; ++jt) {
        const int jcol = (w * 4 + jt) * 16 + l15;
        float bias = b1v[jcol];
        #pragma unroll
        for (int nt = 0; nt < 2; ++nt) {
            #pragma unroll
            for (int r = 0; r < 4; ++r) {
                float v = acc[nt][jt][r] + bias;
                hid[nt * 16 + kg * 4 + r][jcol] = bf16_rne(gelu_f(v));
            }
        }
    }
    __syncthreads();

    // ---- layer 2: wave w -> d-tile w ----
    f32x4 acc2[2];
    #pragma unroll
    for (int a = 0; a < 2; ++a) acc2[a] = f32x4{0.f, 0.f, 0.f, 0.f};

    #pragma unroll
    for (int s = 0; s < 8; ++s) {
        const int kofs = s * 32 + kg * 8;
        bf16x8 bb = *(const bf16x8*)(w2t + (w * 16 + l15) * 256 + kofs);
        #pragma unroll
        for (int nt = 0; nt < 2; ++nt) {
            bf16x8 aa = *(const bf16x8*)&hid[nt * 16 + l15][kofs];
            acc2[nt] = __builtin_amdgcn_mfma_f32_16x16x32_bf16(aa, bb, acc2[nt], 0, 0, 0);
        }
    }

    float bias2 = b2v[w * 16 + l15];
    #pragma unroll
    for (int nt = 0; nt < 2; ++nt) {
        #pragma unroll
        for (int r = 0; r < 4; ++r) {
            int node = node0 + nt * 16 + kg * 4 + r;
            if (node < N_NODES)
                out[(size_t)node * DIM + w * 16 + l15] = acc2[nt][r] + bias2;
        }
    }
}

// ---------------------------------------------------------------------------
extern "C" void kernel_launch(void* const* d_in, const int* in_sizes, int n_in,
                              void* d_out, int out_size, void* d_ws, size_t ws_size,
                              hipStream_t stream) {
    const float* h  = (const float*)d_in[0];
    const int* eidx = (const int*)d_in[1];   // [2, N_EDGES]: src row then dst row
    const float* W1 = (const float*)d_in[2];
    const float* b1 = (const float*)d_in[3];
    const float* W2 = (const float*)d_in[4];
    const float* b2 = (const float*)d_in[5];
    float* out = (float*)d_out;

    const int* src = eidx;
    const int* dst = eidx + N_EDGES;

    // workspace layout
    unsigned short* xb    = (unsigned short*)d_ws;                 // N_NODES*128 ushort
    unsigned short* w1t   = xb + (size_t)N_NODES * 128;            // 32,768
    unsigned short* w2t   = w1t + 128 * 256;                       // 16,384
    unsigned int*   gbuf  = (unsigned int*)(w2t + 256 * 64);       // NCB*MAXBE uint
    unsigned short* csr16 = (unsigned short*)(gbuf + NCB * MAXBE); // NCB*MAXBE ushort
    int*  bcnt = (int*)(csr16 + NCB * MAXBE);                      // NCB
    int2* rng  = (int2*)(bcnt + NCB);                              // N_NODES (8B-aligned)

    prep_kernel<<<(PREP_TOTAL / 4 + 255) / 256, 256, 0, stream>>>(h, W1, W2, xb, w1t, w2t, bcnt);
    partA_kernel<<<ABLKS, 256, 0, stream>>>(src, dst, bcnt, gbuf);
    partB_kernel<<<NCB, 1024, 0, stream>>>(gbuf, bcnt, csr16, rng);
    {
        int grid = (N_NODES + 3) / 4;
        gather_kernel<<<grid, 256, 0, stream>>>(rng, csr16, xb);
    }
    {
        int grid = (N_NODES + 31) / 32;
        mlp_mfma_kernel<<<grid, 256, 0, stream>>>(xb, w1t, w2t, b1, b2, out);
    }
}